// Round 10
// baseline (941.878 us; speedup 1.0000x reference)
//
#include <hip/hip_runtime.h>

#define DIM 128
#define CHUNK 8192          // edges per P1 block
#define NBK 256             // padded bucket count (used: ceil(2N/1024) = 196)
#define BSHIFT 10           // bucket covers 1024 virtual dst ids
#define SCAN_T 256
#define SCAN_E 16           // elements per thread in scan kernels

typedef __attribute__((ext_vector_type(8))) short bf16x8;
typedef __attribute__((ext_vector_type(4))) float f32x4;
typedef __attribute__((ext_vector_type(2))) unsigned u32x2;
typedef __attribute__((ext_vector_type(4))) unsigned u32x4;

static __device__ __forceinline__ short f2bf(float f) {
    union { float f; unsigned u; } v; v.f = f;
    unsigned r = (v.u + 0x7FFF + ((v.u >> 16) & 1)) >> 16;   // RN-even
    return (short)r;
}
static __device__ __forceinline__ float asf(unsigned u) {
    union { unsigned u; float f; } v; v.u = u; return v.f;
}
static __device__ __forceinline__ unsigned asu(float f) {
    union { float f; unsigned u; } v; v.f = f; return v.u;
}
static __device__ __forceinline__ unsigned pk2(float a, float b) {
    return (unsigned)(unsigned short)f2bf(a) | ((unsigned)(unsigned short)f2bf(b) << 16);
}

// ------------- weight prep: pack 3 mats/layer as K=384 x N=128 bf16 --------
struct WPtrs { const float* w[9]; };
__global__ __launch_bounds__(256) void prep_w_k(WPtrs p, short* __restrict__ wt)
{
    const int g = blockIdx.x * 256 + threadIdx.x;   // 3*12*8*64 = 18432
    if (g >= 3 * 12 * 8 * 64) return;
    const int lane = g & 63;
    const int ct   = (g >> 6) & 7;
    const int rest = g >> 9;           // 0..35
    const int ks   = rest % 12;
    const int layer = rest / 12;
    const int mat   = ks >> 2;         // 0..2 within layer (128 rows = 4 ks each)
    const int n     = ct * 16 + (lane & 15);
    const int kbase = (ks & 3) * 32 + (lane >> 4) * 8;
    const float* W = p.w[layer * 3 + mat];
    short* dst = wt + (size_t)layer * 49152 + ks * 4096 + ct * 512 + lane * 8;
#pragma unroll
    for (int j = 0; j < 8; ++j) dst[j] = f2bf(W[(size_t)(kbase + j) * DIM + n]);
}

// ------------- fp32 -> bf16 cast of the input features ----------------------
__global__ __launch_bounds__(256) void cast_k(
    const float* __restrict__ X, short* __restrict__ Xb, int n8)
{
    const int i = blockIdx.x * 256 + threadIdx.x;
    if (i >= n8) return;
    const float4* xp = (const float4*)X + (size_t)i * 2;
    const float4 a = xp[0];
    const float4 b = xp[1];
    bf16x8 v;
    v[0] = f2bf(a.x); v[1] = f2bf(a.y); v[2] = f2bf(a.z); v[3] = f2bf(a.w);
    v[4] = f2bf(b.x); v[5] = f2bf(b.y); v[6] = f2bf(b.z); v[7] = f2bf(b.w);
    *(bf16x8*)(Xb + (size_t)i * 8) = v;
}

// =================== CSR build v3: global fine hist+scan, bucket staging ====
// virtual dst id v in [0, 2N): v = dst (adj1), N + dst (adj2).
// bucket = v >> 10; binned elem: x = src | (vlow << 17), y = w bits.
// Order: hist2 (global per-dst hist) -> scan1/2/3 (rowptr + per-dst cursor)
//        -> bkt (bucket bases from rowptr) -> p1_bin (bucket-contiguous
//        staging, proven r4) -> p2s (bucket-CONFINED scatter: pairs writes
//        land in a 128 KB L2-resident window; avoids r6's full-range
//        write amplification AND r4-p2's 40-barrier LDS scan).

__global__ __launch_bounds__(256) void hist2_k(
    const int* __restrict__ d1, const int* __restrict__ d2,
    int* __restrict__ cnt, int N, int E, int E2)
{
    const int stride = gridDim.x * 256;
    for (int i = blockIdx.x * 256 + threadIdx.x; i < E;  i += stride)
        atomicAdd(&cnt[d1[i]], 1);
    for (int i = blockIdx.x * 256 + threadIdx.x; i < E2; i += stride)
        atomicAdd(&cnt[N + d2[i]], 1);
}

__global__ __launch_bounds__(256) void scan1_k(
    const int* __restrict__ cnt, int* __restrict__ partial, int total)
{
    __shared__ int sd[SCAN_T];
    const int t = threadIdx.x;
    const int base = blockIdx.x * SCAN_T * SCAN_E + t * SCAN_E;
    int s = 0;
#pragma unroll
    for (int j = 0; j < SCAN_E; ++j) {
        const int idx = base + j;
        if (idx < total) s += cnt[idx];
    }
    sd[t] = s;
    __syncthreads();
    for (int off = 128; off > 0; off >>= 1) {
        if (t < off) sd[t] += sd[t + off];
        __syncthreads();
    }
    if (t == 0) partial[blockIdx.x] = sd[0];
}

__global__ void scan2_k(int* __restrict__ partial, int nblk,
                        int* __restrict__ rowptr, int twoN, int ET)
{
    if (threadIdx.x == 0 && blockIdx.x == 0) {
        int run = 0;
        for (int i = 0; i < nblk; ++i) { const int v = partial[i]; partial[i] = run; run += v; }
        rowptr[twoN] = ET;
    }
}

__global__ __launch_bounds__(256) void scan3_k(
    const int* __restrict__ cnt, const int* __restrict__ partial,
    int* __restrict__ rowptr, int* __restrict__ cursor, int total)
{
    __shared__ int sd[SCAN_T];
    const int t = threadIdx.x;
    const int base = blockIdx.x * SCAN_T * SCAN_E + t * SCAN_E;
    int loc[SCAN_E];
    int s = 0;
#pragma unroll
    for (int j = 0; j < SCAN_E; ++j) {
        const int idx = base + j;
        const int v = (idx < total) ? cnt[idx] : 0;
        loc[j] = v; s += v;
    }
    sd[t] = s;
    __syncthreads();
    for (int off = 1; off < SCAN_T; off <<= 1) {
        const int a = (t >= off) ? sd[t - off] : 0;
        __syncthreads();
        sd[t] += a;
        __syncthreads();
    }
    int excl = sd[t] - s + partial[blockIdx.x];
#pragma unroll
    for (int j = 0; j < SCAN_E; ++j) {
        const int idx = base + j;
        if (idx < total) { rowptr[idx] = excl; cursor[idx] = excl; excl += loc[j]; }
    }
}

// bucket bases from rowptr: bktbase[b] = rowptr[b<<10]; cursorB = copy.
__global__ __launch_bounds__(256) void bkt_k(
    const int* __restrict__ rowptr, int* __restrict__ bktbase,
    int* __restrict__ cursorB, int nbk, int twoN, int ET)
{
    const int b = blockIdx.x * 256 + threadIdx.x;
    if (b > nbk) return;
    const int v = b << BSHIFT;
    const int val = (v < twoN) ? rowptr[v] : ET;
    bktbase[b] = val;
    if (b < nbk) cursorB[b] = val;
}

__global__ __launch_bounds__(256) void p1_bin_k(
    const int* __restrict__ s1, const int* __restrict__ d1, const float* __restrict__ ea1,
    const int* __restrict__ s2, const int* __restrict__ d2, const float* __restrict__ ea2,
    int* __restrict__ cursorB, uint2* __restrict__ binned,
    int N, int E, int E2, int nc1)
{
    __shared__ __align__(16) uint2 stage[CHUNK];     // 64 KB
    __shared__ unsigned char lbkt[CHUNK];            // 8 KB
    __shared__ int hist[NBK], exclv[NBK], lcur[NBK], gpos[NBK];

    const int t = threadIdx.x;
    const int c = blockIdx.x;
    const bool a2 = (c >= nc1);
    const int* S  = a2 ? s2  : s1;
    const int* D  = a2 ? d2  : d1;
    const float* W = a2 ? ea2 : ea1;
    const int Eloc = a2 ? E2 : E;
    const int voff = a2 ? N : 0;
    const int eb   = (a2 ? (c - nc1) : c) * CHUNK;
    const int ec   = min(CHUNK, Eloc - eb);

    hist[t] = 0;
    __syncthreads();

    for (int i = t; i < ec; i += 256)
        atomicAdd(&hist[(unsigned)(voff + D[eb + i]) >> BSHIFT], 1);
    __syncthreads();

    exclv[t] = hist[t];
    __syncthreads();
    for (int off = 1; off < NBK; off <<= 1) {
        int a = (t >= off) ? exclv[t - off] : 0;
        __syncthreads();
        exclv[t] += a;
        __syncthreads();
    }
    const int myincl = exclv[t];
    __syncthreads();
    exclv[t] = myincl - hist[t];
    lcur[t]  = exclv[t];
    if (hist[t]) gpos[t] = atomicAdd(&cursorB[t], hist[t]);
    __syncthreads();

    for (int i = t; i < ec; i += 256) {
        const int v = voff + D[eb + i];
        const int b = (unsigned)v >> BSHIFT;
        const int lpos = atomicAdd(&lcur[b], 1);
        stage[lpos] = make_uint2((unsigned)S[eb + i] | ((unsigned)(v & 1023) << 17),
                                 asu(W[eb + i]));
        lbkt[lpos] = (unsigned char)b;
    }
    __syncthreads();

    for (int s = t; s < ec; s += 256) {
        const int b = lbkt[s];
        binned[gpos[b] + (s - exclv[b])] = stage[s];
    }
}

// bucket-confined scatter: no LDS, no barriers; writes within 128 KB window.
__global__ __launch_bounds__(256) void p2s_k(
    const uint2* __restrict__ binned, const int* __restrict__ bktbase,
    int* __restrict__ cursor, uint2* __restrict__ pairs)
{
    const int b = blockIdx.x;
    const int base = bktbase[b];
    const int cnt  = bktbase[b + 1] - base;
    const int vbase = b << BSHIFT;
    for (int i = threadIdx.x; i < cnt; i += 256) {
        const uint2 e = binned[base + i];
        const int v = vbase + (int)(e.x >> 17);
        const int pos = atomicAdd(&cursor[v], 1);
        pairs[pos] = make_uint2(e.x & 0x1FFFFu, e.y);
    }
}

// ---------------- gather inner loop (16 lanes per node, 16 B/lane) ----------
static __device__ __forceinline__ void bf2acc8(unsigned w, u32x4 h, float* acc)
{
    const float wf = asf(w);
    acc[0] = fmaf(wf, asf(h.x << 16),         acc[0]);
    acc[1] = fmaf(wf, asf(h.x & 0xFFFF0000u), acc[1]);
    acc[2] = fmaf(wf, asf(h.y << 16),         acc[2]);
    acc[3] = fmaf(wf, asf(h.y & 0xFFFF0000u), acc[3]);
    acc[4] = fmaf(wf, asf(h.z << 16),         acc[4]);
    acc[5] = fmaf(wf, asf(h.z & 0xFFFF0000u), acc[5]);
    acc[6] = fmaf(wf, asf(h.w << 16),         acc[6]);
    acc[7] = fmaf(wf, asf(h.w & 0xFFFF0000u), acc[7]);
}

static __device__ __forceinline__ void gacc16(
    const short* __restrict__ H, const uint2* __restrict__ pairs,
    int start, int end, int s, float* acc)
{
    int j = start;
    for (; j + 7 < end; j += 8) {
        u32x2 p[8]; u32x4 h[8];
#pragma unroll
        for (int q = 0; q < 8; ++q)
            p[q] = __builtin_nontemporal_load((const u32x2*)(pairs + j + q));
#pragma unroll
        for (int q = 0; q < 8; ++q)
            h[q] = *(const u32x4*)(H + (size_t)p[q].x * DIM + s * 8);
#pragma unroll
        for (int q = 0; q < 8; ++q) bf2acc8(p[q].y, h[q], acc);
    }
    if (j + 3 < end) {
        u32x2 p[4]; u32x4 h[4];
#pragma unroll
        for (int q = 0; q < 4; ++q)
            p[q] = __builtin_nontemporal_load((const u32x2*)(pairs + j + q));
#pragma unroll
        for (int q = 0; q < 4; ++q)
            h[q] = *(const u32x4*)(H + (size_t)p[q].x * DIM + s * 8);
#pragma unroll
        for (int q = 0; q < 4; ++q) bf2acc8(p[q].y, h[q], acc);
        j += 4;
    }
    for (; j < end; ++j) {
        const u32x2 p = __builtin_nontemporal_load((const u32x2*)(pairs + j));
        const u32x4 h = *(const u32x4*)(H + (size_t)p.x * DIM + s * 8);
        bf2acc8(p.y, h, acc);
    }
}

// ------------- fused layer (r7-proven): gather G1,G2 -> LDS, K=384 MFMA -----
// Y = [Xb | G1 | G2] @ [W0;W1;W2] + (b0+b1+b2).
// 33% occupancy is the L2-friendly operating point (r8/r9: higher occ
// inflates FETCH+WRITE and is slower). Do not raise concurrency here.
__global__ __launch_bounds__(256, 5) void fused_layer_k(
    const short* __restrict__ Xb, const short* __restrict__ Wp,
    const uint2* __restrict__ pairs, const int* __restrict__ rowptr,
    const float* __restrict__ b0, const float* __restrict__ b1,
    const float* __restrict__ b2,
    float* __restrict__ Yf, short* __restrict__ Yb, int N)
{
    __shared__ __align__(16) short As[64][256];   // G1 slots 0..15, G2 slots 16..31 (16B slots)
    const int t  = threadIdx.x;
    const int m0 = blockIdx.x * 64;

    // ---- gather phase: 16 lanes/node, 16 nodes concurrent, 4 groups ----
    const int s    = t & 15;
    const int nrow = t >> 4;              // 0..15
#pragma unroll
    for (int nl = 0; nl < 4; ++nl) {
        const int r    = nl * 16 + nrow;
        const int node = m0 + r;
        float a1[8] = {0.f,0.f,0.f,0.f,0.f,0.f,0.f,0.f};
        float a2[8] = {0.f,0.f,0.f,0.f,0.f,0.f,0.f,0.f};
        if (node < N) {
            gacc16(Xb, pairs, rowptr[node],     rowptr[node + 1],     s, a1);
            gacc16(Xb, pairs, rowptr[N + node], rowptr[N + node + 1], s, a2);
        }
        u32x4 o1 = (u32x4){pk2(a1[0], a1[1]), pk2(a1[2], a1[3]),
                           pk2(a1[4], a1[5]), pk2(a1[6], a1[7])};
        u32x4 o2 = (u32x4){pk2(a2[0], a2[1]), pk2(a2[2], a2[3]),
                           pk2(a2[4], a2[5]), pk2(a2[6], a2[7])};
        const int sw = s ^ (r & 7);
        *(u32x4*)&As[r][sw * 8]        = o1;
        *(u32x4*)&As[r][128 + sw * 8]  = o2;   // slot 16+sw
    }
    __syncthreads();

    // ---- MFMA phase ----
    const int wave  = t >> 6;
    const int lane  = t & 63;
    const int l15   = lane & 15;
    const int kq    = lane >> 4;
    const int mbase = wave * 16;
    const int mrow  = m0 + mbase + l15;
    const int mclmp = (mrow < N) ? mrow : (N - 1);
    const short* xrow = Xb + (size_t)mclmp * DIM + kq * 8;

    f32x4 acc[8];
#pragma unroll
    for (int ct = 0; ct < 8; ++ct) acc[ct] = (f32x4){0.f, 0.f, 0.f, 0.f};

#pragma unroll
    for (int ks = 0; ks < 4; ++ks) {
        const bf16x8 a = *(const bf16x8*)(xrow + ks * 32);
        const short* wb = Wp + ks * 4096 + lane * 8;
#pragma unroll
        for (int ct = 0; ct < 8; ++ct)
            acc[ct] = __builtin_amdgcn_mfma_f32_16x16x32_bf16(
                a, *(const bf16x8*)(wb + ct * 512), acc[ct], 0, 0, 0);
    }
#pragma unroll
    for (int ks = 4; ks < 12; ++ks) {
        const int lin  = (ks - 4) * 4 + kq;          // 0..31
        const int row  = mbase + l15;
        const int slot = (lin & 16) | ((lin & 15) ^ (row & 7));
        const bf16x8 a = *(const bf16x8*)&As[row][slot * 8];
        const short* wb = Wp + ks * 4096 + lane * 8;
#pragma unroll
        for (int ct = 0; ct < 8; ++ct)
            acc[ct] = __builtin_amdgcn_mfma_f32_16x16x32_bf16(
                a, *(const bf16x8*)(wb + ct * 512), acc[ct], 0, 0, 0);
    }

    // D: col = ct*16 + (lane&15), row = (lane>>4)*4 + r
#pragma unroll
    for (int ct = 0; ct < 8; ++ct) {
        const int col = ct * 16 + l15;
        const float bias = b0[col] + b1[col] + b2[col];
#pragma unroll
        for (int r = 0; r < 4; ++r) {
            const int m = m0 + mbase + kq * 4 + r;
            if (m >= N) continue;
            const float v = acc[ct][r] + bias;
            if (Yf) __builtin_nontemporal_store(v, &Yf[(size_t)m * DIM + col]);
            else    Yb[(size_t)m * DIM + col] = f2bf(v);
        }
    }
}

extern "C" void kernel_launch(void* const* d_in, const int* in_sizes, int n_in,
                              void* d_out, int out_size, void* d_ws, size_t ws_size,
                              hipStream_t stream)
{
    const float* x   = (const float*)d_in[0];
    const int*   ei  = (const int*)d_in[1];
    const float* ea  = (const float*)d_in[2];
    const int*   ei2 = (const int*)d_in[3];
    const float* ea2 = (const float*)d_in[4];

    const int N  = in_sizes[0] / DIM;
    const int E  = in_sizes[2];
    const int E2 = in_sizes[4];
    const int ET = E + E2;
    const int twoN = 2 * N;

    float* OUT = (float*)d_out;

    // ---- workspace layout (~106 MB) ----
    short* Xb0 = (short*)d_ws;                        // N*DIM bf16
    short* Xb1 = Xb0 + (size_t)N * DIM;               // N*DIM bf16
    short* WT  = Xb1 + (size_t)N * DIM;               // 3*49152 bf16 (packed K=384)
    int*   rowptr = (int*)(WT + 3 * 49152);           // 2N+1 (pad 2N+4)
    int*   cnt    = rowptr + twoN + 4;                // 2N fine hist
    int*   cursor = cnt + twoN;                       // 2N per-dst cursor
    int*   partial= cursor + twoN;                    // scan partials (<=256)
    int*   bktbase= partial + 256;                    // NBK+4
    int*   cursorB= bktbase + NBK + 4;                // NBK
    uint2* pairs  = (uint2*)(cursorB + NBK);          // ET * 8B
    uint2* binned = pairs + ET;                       // ET * 8B (dead after CSR)

    // ---- weight prep ----
    WPtrs wp;
    for (int b = 0; b < 3; ++b) {
        wp.w[b * 3 + 0] = (const float*)d_in[5 + 6 * b + 0];
        wp.w[b * 3 + 1] = (const float*)d_in[5 + 6 * b + 2];
        wp.w[b * 3 + 2] = (const float*)d_in[5 + 6 * b + 4];
    }
    prep_w_k<<<(18432 + 255) / 256, 256, 0, stream>>>(wp, WT);

    // ---- input cast to bf16 ----
    const int n8 = N * DIM / 8;
    cast_k<<<(n8 + 255) / 256, 256, 0, stream>>>(x, Xb0, n8);

    // ---- CSR build v3 ----
    const int nc1 = (E + CHUNK - 1) / CHUNK;
    const int nc2 = (E2 + CHUNK - 1) / CHUNK;
    const int nbk_used = (twoN + (1 << BSHIFT) - 1) >> BSHIFT;   // <= NBK
    const int nscan = (twoN + SCAN_T * SCAN_E - 1) / (SCAN_T * SCAN_E);

    hipMemsetAsync(cnt, 0, (size_t)twoN * sizeof(int), stream);
    hist2_k<<<1024, 256, 0, stream>>>(ei + E, ei2 + E2, cnt, N, E, E2);
    scan1_k<<<nscan, 256, 0, stream>>>(cnt, partial, twoN);
    scan2_k<<<1, 64, 0, stream>>>(partial, nscan, rowptr, twoN, ET);
    scan3_k<<<nscan, 256, 0, stream>>>(cnt, partial, rowptr, cursor, twoN);
    bkt_k<<<1, 256, 0, stream>>>(rowptr, bktbase, cursorB, nbk_used, twoN, ET);
    p1_bin_k<<<nc1 + nc2, 256, 0, stream>>>(ei, ei + E, ea, ei2, ei2 + E2, ea2,
                                            cursorB, binned, N, E, E2, nc1);
    p2s_k<<<nbk_used, 256, 0, stream>>>(binned, bktbase, cursor, pairs);

    // ---- 3 inception blocks: fused gather + K=384 GEMM per layer ----
    const int gGemm = (N + 63) / 64;

    const short* cur = Xb0;
    for (int b = 0; b < 3; ++b) {
        const float* lnb = (const float*)d_in[5 + 6 * b + 1];
        const float* c1b = (const float*)d_in[5 + 6 * b + 3];
        const float* c2b = (const float*)d_in[5 + 6 * b + 5];

        float* yf = (b == 2) ? OUT : nullptr;
        short* yb = (b == 2) ? nullptr : ((cur == Xb0) ? Xb1 : Xb0);

        fused_layer_k<<<gGemm, 256, 0, stream>>>(
            cur, WT + (size_t)b * 49152, pairs, rowptr, lnb, c1b, c2b, yf, yb, N);

        if (b < 2) cur = yb;
    }
}

// Round 11
// 796.688 us; speedup vs baseline: 1.1822x; 1.1822x over previous
//
#include <hip/hip_runtime.h>

#define DIM 128
#define CHUNK 8192          // edges per P1 block
#define NBK 256             // padded bucket count (used: ceil(2N/1024) = 196)
#define BSHIFT 10           // bucket covers 1024 virtual dst ids

typedef __attribute__((ext_vector_type(8))) short bf16x8;
typedef __attribute__((ext_vector_type(4))) float f32x4;
typedef __attribute__((ext_vector_type(2))) unsigned u32x2;
typedef __attribute__((ext_vector_type(4))) unsigned u32x4;

static __device__ __forceinline__ short f2bf(float f) {
    union { float f; unsigned u; } v; v.f = f;
    unsigned r = (v.u + 0x7FFF + ((v.u >> 16) & 1)) >> 16;   // RN-even
    return (short)r;
}
static __device__ __forceinline__ float asf(unsigned u) {
    union { unsigned u; float f; } v; v.u = u; return v.f;
}
static __device__ __forceinline__ unsigned asu(float f) {
    union { float f; unsigned u; } v; v.f = f; return v.u;
}
static __device__ __forceinline__ unsigned pk2(float a, float b) {
    return (unsigned)(unsigned short)f2bf(a) | ((unsigned)(unsigned short)f2bf(b) << 16);
}

// ------------- weight prep: pack 3 mats/layer as K=384 x N=128 bf16 --------
// Per layer: frag (ks12, ct8) at layer*49152 + (ks*8 + ct)*512 + lane*8 + j.
// lane l holds 8 bf16: n = ct*16 + (l&15), kk = ks*32 + (l>>4)*8 + j,
// source mat = kk/128 (0=ln, 1=c1, 2=c2), krow = kk%128.
struct WPtrs { const float* w[9]; };
__global__ __launch_bounds__(256) void prep_w_k(WPtrs p, short* __restrict__ wt)
{
    const int g = blockIdx.x * 256 + threadIdx.x;   // 3*12*8*64 = 18432
    if (g >= 3 * 12 * 8 * 64) return;
    const int lane = g & 63;
    const int ct   = (g >> 6) & 7;
    const int rest = g >> 9;           // 0..35
    const int ks   = rest % 12;
    const int layer = rest / 12;
    const int mat   = ks >> 2;         // 0..2 within layer (128 rows = 4 ks each)
    const int n     = ct * 16 + (lane & 15);
    const int kbase = (ks & 3) * 32 + (lane >> 4) * 8;
    const float* W = p.w[layer * 3 + mat];
    short* dst = wt + (size_t)layer * 49152 + ks * 4096 + ct * 512 + lane * 8;
#pragma unroll
    for (int j = 0; j < 8; ++j) dst[j] = f2bf(W[(size_t)(kbase + j) * DIM + n]);
}

// ------------- fp32 -> bf16 cast of the input features ----------------------
__global__ __launch_bounds__(256) void cast_k(
    const float* __restrict__ X, short* __restrict__ Xb, int n8)
{
    const int i = blockIdx.x * 256 + threadIdx.x;
    if (i >= n8) return;
    const float4* xp = (const float4*)X + (size_t)i * 2;
    const float4 a = xp[0];
    const float4 b = xp[1];
    bf16x8 v;
    v[0] = f2bf(a.x); v[1] = f2bf(a.y); v[2] = f2bf(a.z); v[3] = f2bf(a.w);
    v[4] = f2bf(b.x); v[5] = f2bf(b.y); v[6] = f2bf(b.z); v[7] = f2bf(b.w);
    *(bf16x8*)(Xb + (size_t)i * 8) = v;
}

// =================== binned CSR build (r4/r7 proven version) ================
// virtual dst id v in [0, 2N): v = dst (adj1), N + dst (adj2).
// bucket = v >> 10 (196 used); vlow = v & 1023.
// binned elem: x = src | (vlow << 17)   (src < 2^17), y = w bits.

__global__ __launch_bounds__(256) void p0_bhist_k(
    const int* __restrict__ d1, const int* __restrict__ d2,
    int* __restrict__ bcnt, int N, int E, int E2)
{
    __shared__ int lh[NBK];
    const int t = threadIdx.x;
    lh[t] = 0;
    __syncthreads();
    const int stride = gridDim.x * 256;
    for (int i = blockIdx.x * 256 + t; i < E;  i += stride) atomicAdd(&lh[d1[i] >> BSHIFT], 1);
    for (int i = blockIdx.x * 256 + t; i < E2; i += stride) atomicAdd(&lh[(N + d2[i]) >> BSHIFT], 1);
    __syncthreads();
    if (lh[t]) atomicAdd(&bcnt[t], lh[t]);
}

__global__ __launch_bounds__(256) void bscan_k(
    const int* __restrict__ bcnt, int* __restrict__ bktbase,
    int* __restrict__ cursor, int* __restrict__ rowptr, int twoN, int ET)
{
    __shared__ int sv[NBK];
    const int t = threadIdx.x;
    sv[t] = bcnt[t];
    __syncthreads();
    for (int off = 1; off < NBK; off <<= 1) {
        int a = (t >= off) ? sv[t - off] : 0;
        __syncthreads();
        sv[t] += a;
        __syncthreads();
    }
    const int excl = t ? sv[t - 1] : 0;
    bktbase[t] = excl;
    cursor[t]  = excl;
    if (t == 0) rowptr[twoN] = ET;
}

__global__ __launch_bounds__(256) void p1_bin_k(
    const int* __restrict__ s1, const int* __restrict__ d1, const float* __restrict__ ea1,
    const int* __restrict__ s2, const int* __restrict__ d2, const float* __restrict__ ea2,
    int* __restrict__ cursor, uint2* __restrict__ binned,
    int N, int E, int E2, int nc1)
{
    __shared__ __align__(16) uint2 stage[CHUNK];     // 64 KB
    __shared__ unsigned char lbkt[CHUNK];            // 8 KB
    __shared__ int hist[NBK], exclv[NBK], lcur[NBK], gpos[NBK];

    const int t = threadIdx.x;
    const int c = blockIdx.x;
    const bool a2 = (c >= nc1);
    const int* S  = a2 ? s2  : s1;
    const int* D  = a2 ? d2  : d1;
    const float* W = a2 ? ea2 : ea1;
    const int Eloc = a2 ? E2 : E;
    const int voff = a2 ? N : 0;
    const int eb   = (a2 ? (c - nc1) : c) * CHUNK;
    const int ec   = min(CHUNK, Eloc - eb);

    hist[t] = 0;
    __syncthreads();

    for (int i = t; i < ec; i += 256)
        atomicAdd(&hist[(unsigned)(voff + D[eb + i]) >> BSHIFT], 1);
    __syncthreads();

    exclv[t] = hist[t];
    __syncthreads();
    for (int off = 1; off < NBK; off <<= 1) {
        int a = (t >= off) ? exclv[t - off] : 0;
        __syncthreads();
        exclv[t] += a;
        __syncthreads();
    }
    const int myincl = exclv[t];
    __syncthreads();
    exclv[t] = myincl - hist[t];
    lcur[t]  = exclv[t];
    if (hist[t]) gpos[t] = atomicAdd(&cursor[t], hist[t]);
    __syncthreads();

    for (int i = t; i < ec; i += 256) {
        const int v = voff + D[eb + i];
        const int b = (unsigned)v >> BSHIFT;
        const int lpos = atomicAdd(&lcur[b], 1);
        stage[lpos] = make_uint2((unsigned)S[eb + i] | ((unsigned)(v & 1023) << 17),
                                 asu(W[eb + i]));
        lbkt[lpos] = (unsigned char)b;
    }
    __syncthreads();

    for (int s = t; s < ec; s += 256) {
        const int b = lbkt[s];
        binned[gpos[b] + (s - exclv[b])] = stage[s];
    }
}

__global__ __launch_bounds__(256) void p2_final_k(
    const uint2* __restrict__ binned, const int* __restrict__ bktbase,
    int* __restrict__ rowptr, uint2* __restrict__ pairs, int twoN)
{
    __shared__ int hist[1024], scn[1024], lcur[1024];
    const int t = threadIdx.x;
    const int b = blockIdx.x;
    const int base = bktbase[b];
    const int cnt  = bktbase[b + 1] - base;
    const int vbase = b << BSHIFT;

    for (int i = t; i < 1024; i += 256) hist[i] = 0;
    __syncthreads();

    for (int i = t; i < cnt; i += 256)
        atomicAdd(&hist[binned[base + i].x >> 17], 1);
    __syncthreads();

    for (int i = t; i < 1024; i += 256) scn[i] = hist[i];
    __syncthreads();
    for (int off = 1; off < 1024; off <<= 1) {
        int a0 = (t       >= off) ? scn[t       - off] : 0;
        int a1 = (t + 256 >= off) ? scn[t + 256 - off] : 0;
        int a2 = (t + 512 >= off) ? scn[t + 512 - off] : 0;
        int a3 = (t + 768 >= off) ? scn[t + 768 - off] : 0;
        __syncthreads();
        scn[t] += a0; scn[t + 256] += a1; scn[t + 512] += a2; scn[t + 768] += a3;
        __syncthreads();
    }
    for (int i = t; i < 1024; i += 256) {
        const int excl = scn[i] - hist[i];
        lcur[i] = excl;
        const int v = vbase + i;
        if (v < twoN) rowptr[v] = base + excl;
    }
    __syncthreads();

    for (int i = t; i < cnt; i += 256) {
        const uint2 e = binned[base + i];
        const int vlow = e.x >> 17;
        const int pos = base + atomicAdd(&lcur[vlow], 1);
        pairs[pos] = make_uint2(e.x & 0x1FFFFu, e.y);
    }
}

// ---------------- gather (r3-proven): 16 lanes/node, 16 B/lane --------------
static __device__ __forceinline__ void bf2acc8(unsigned w, u32x4 h, float* acc)
{
    const float wf = asf(w);
    acc[0] = fmaf(wf, asf(h.x << 16),         acc[0]);
    acc[1] = fmaf(wf, asf(h.x & 0xFFFF0000u), acc[1]);
    acc[2] = fmaf(wf, asf(h.y << 16),         acc[2]);
    acc[3] = fmaf(wf, asf(h.y & 0xFFFF0000u), acc[3]);
    acc[4] = fmaf(wf, asf(h.z << 16),         acc[4]);
    acc[5] = fmaf(wf, asf(h.z & 0xFFFF0000u), acc[5]);
    acc[6] = fmaf(wf, asf(h.w << 16),         acc[6]);
    acc[7] = fmaf(wf, asf(h.w & 0xFFFF0000u), acc[7]);
}

static __device__ __forceinline__ void gacc16(
    const short* __restrict__ H, const uint2* __restrict__ pairs,
    int start, int end, int s, float* acc)
{
    int j = start;
    for (; j + 7 < end; j += 8) {
        u32x2 p[8]; u32x4 h[8];
#pragma unroll
        for (int q = 0; q < 8; ++q)
            p[q] = __builtin_nontemporal_load((const u32x2*)(pairs + j + q));
#pragma unroll
        for (int q = 0; q < 8; ++q)
            h[q] = *(const u32x4*)(H + (size_t)p[q].x * DIM + s * 8);
#pragma unroll
        for (int q = 0; q < 8; ++q) bf2acc8(p[q].y, h[q], acc);
    }
    if (j + 3 < end) {
        u32x2 p[4]; u32x4 h[4];
#pragma unroll
        for (int q = 0; q < 4; ++q)
            p[q] = __builtin_nontemporal_load((const u32x2*)(pairs + j + q));
#pragma unroll
        for (int q = 0; q < 4; ++q)
            h[q] = *(const u32x4*)(H + (size_t)p[q].x * DIM + s * 8);
#pragma unroll
        for (int q = 0; q < 4; ++q) bf2acc8(p[q].y, h[q], acc);
        j += 4;
    }
    for (; j < end; ++j) {
        const u32x2 p = __builtin_nontemporal_load((const u32x2*)(pairs + j));
        const u32x4 h = *(const u32x4*)(H + (size_t)p.x * DIM + s * 8);
        bf2acc8(p.y, h, acc);
    }
}

__global__ __launch_bounds__(256) void gatherX_k(
    const short* __restrict__ Xb,
    const uint2* __restrict__ pairs, const int* __restrict__ rowptr,
    short* __restrict__ G1, short* __restrict__ G2, int N)
{
    const int node = blockIdx.x * 16 + (threadIdx.x >> 4);
    if (node >= N) return;
    const int s = threadIdx.x & 15;

    const int s1 = rowptr[node];
    const int e1 = rowptr[node + 1];
    const int s2 = rowptr[N + node];
    const int e2 = rowptr[N + node + 1];

    float a1[8] = {0.f, 0.f, 0.f, 0.f, 0.f, 0.f, 0.f, 0.f};
    float a2[8] = {0.f, 0.f, 0.f, 0.f, 0.f, 0.f, 0.f, 0.f};
    gacc16(Xb, pairs, s1, e1, s, a1);
    gacc16(Xb, pairs, s2, e2, s, a2);

    const size_t off = (size_t)node * DIM + s * 8;
    u32x4 o1 = (u32x4){pk2(a1[0], a1[1]), pk2(a1[2], a1[3]),
                       pk2(a1[4], a1[5]), pk2(a1[6], a1[7])};
    u32x4 o2 = (u32x4){pk2(a2[0], a2[1]), pk2(a2[2], a2[3]),
                       pk2(a2[4], a2[5]), pk2(a2[6], a2[7])};
    __builtin_nontemporal_store(o1, (u32x4*)(G1 + off));
    __builtin_nontemporal_store(o2, (u32x4*)(G2 + off));
}

// ------------- lean K=384 GEMM: zero LDS, zero barriers ---------------------
// Y = [Xb | G1 | G2] @ [W0;W1;W2] + (b0+b1+b2).
// A-fragments: each wave's 16 rows are wave-local -> read direct from global
// (Xb L2-hot seq; G1/G2 nt read-once streams). B direct from 96 KB L2-hot Wp
// (r7-proven pattern). 8 blocks/CU thread-limited occupancy.
__global__ __launch_bounds__(256, 8) void gemm_k(
    const short* __restrict__ Xb, const short* __restrict__ G1,
    const short* __restrict__ G2, const short* __restrict__ Wp,
    const float* __restrict__ b0, const float* __restrict__ b1,
    const float* __restrict__ b2,
    float* __restrict__ Yf, short* __restrict__ Yb, int N)
{
    const int t     = threadIdx.x;
    const int wave  = t >> 6;
    const int lane  = t & 63;
    const int l15   = lane & 15;
    const int kq    = lane >> 4;
    const int mbase = blockIdx.x * 64 + wave * 16;
    const int mrow  = mbase + l15;
    const int mclmp = (mrow < N) ? mrow : (N - 1);
    const size_t ro = (size_t)mclmp * DIM + kq * 8;

    f32x4 acc[8];
#pragma unroll
    for (int ct = 0; ct < 8; ++ct) acc[ct] = (f32x4){0.f, 0.f, 0.f, 0.f};

#pragma unroll
    for (int ks = 0; ks < 4; ++ks) {
        const bf16x8 a = *(const bf16x8*)(Xb + ro + ks * 32);
        const short* wb = Wp + ks * 4096 + lane * 8;
#pragma unroll
        for (int ct = 0; ct < 8; ++ct)
            acc[ct] = __builtin_amdgcn_mfma_f32_16x16x32_bf16(
                a, *(const bf16x8*)(wb + ct * 512), acc[ct], 0, 0, 0);
    }
#pragma unroll
    for (int ks = 4; ks < 8; ++ks) {
        const bf16x8 a = __builtin_nontemporal_load(
            (const bf16x8*)(G1 + ro + (ks - 4) * 32));
        const short* wb = Wp + ks * 4096 + lane * 8;
#pragma unroll
        for (int ct = 0; ct < 8; ++ct)
            acc[ct] = __builtin_amdgcn_mfma_f32_16x16x32_bf16(
                a, *(const bf16x8*)(wb + ct * 512), acc[ct], 0, 0, 0);
    }
#pragma unroll
    for (int ks = 8; ks < 12; ++ks) {
        const bf16x8 a = __builtin_nontemporal_load(
            (const bf16x8*)(G2 + ro + (ks - 8) * 32));
        const short* wb = Wp + ks * 4096 + lane * 8;
#pragma unroll
        for (int ct = 0; ct < 8; ++ct)
            acc[ct] = __builtin_amdgcn_mfma_f32_16x16x32_bf16(
                a, *(const bf16x8*)(wb + ct * 512), acc[ct], 0, 0, 0);
    }

    // D: col = ct*16 + (lane&15), row = (lane>>4)*4 + r
#pragma unroll
    for (int ct = 0; ct < 8; ++ct) {
        const int col = ct * 16 + l15;
        const float bias = b0[col] + b1[col] + b2[col];
#pragma unroll
        for (int r = 0; r < 4; ++r) {
            const int m = mbase + kq * 4 + r;
            if (m >= N) continue;
            const float v = acc[ct][r] + bias;
            if (Yf) __builtin_nontemporal_store(v, &Yf[(size_t)m * DIM + col]);
            else    Yb[(size_t)m * DIM + col] = f2bf(v);
        }
    }
}

extern "C" void kernel_launch(void* const* d_in, const int* in_sizes, int n_in,
                              void* d_out, int out_size, void* d_ws, size_t ws_size,
                              hipStream_t stream)
{
    const float* x   = (const float*)d_in[0];
    const int*   ei  = (const int*)d_in[1];
    const float* ea  = (const float*)d_in[2];
    const int*   ei2 = (const int*)d_in[3];
    const float* ea2 = (const float*)d_in[4];

    const int N  = in_sizes[0] / DIM;
    const int E  = in_sizes[2];
    const int E2 = in_sizes[4];
    const int ET = E + E2;

    float* OUT = (float*)d_out;

    // ---- workspace layout (~129 MB) ----
    short* Xb0 = (short*)d_ws;                        // N*DIM bf16
    short* Xb1 = Xb0 + (size_t)N * DIM;               // N*DIM bf16
    short* G1  = Xb1 + (size_t)N * DIM;               // N*DIM bf16 (binned aliases)
    short* G2  = G1  + (size_t)N * DIM;               // N*DIM bf16
    short* WT  = G2  + (size_t)N * DIM;               // 3*49152 bf16 (packed K=384)
    int*   rowptr = (int*)(WT + 3 * 49152);           // 2N+1 (pad 2N+4)
    int*   bcnt   = rowptr + 2 * N + 4;               // NBK
    int*   bktbase= bcnt + NBK;                       // NBK+1 -> pad NBK+4
    int*   cursor = bktbase + NBK + 4;                // NBK
    uint2* pairs  = (uint2*)(cursor + NBK);           // ET * 8B
    uint2* binned = (uint2*)G1;                       // ET*8B == N*DIM*2 exactly; dead before gather

    // ---- weight prep ----
    WPtrs wp;
    for (int b = 0; b < 3; ++b) {
        wp.w[b * 3 + 0] = (const float*)d_in[5 + 6 * b + 0];
        wp.w[b * 3 + 1] = (const float*)d_in[5 + 6 * b + 2];
        wp.w[b * 3 + 2] = (const float*)d_in[5 + 6 * b + 4];
    }
    prep_w_k<<<(18432 + 255) / 256, 256, 0, stream>>>(wp, WT);

    // ---- input cast to bf16 ----
    const int n8 = N * DIM / 8;
    cast_k<<<(n8 + 255) / 256, 256, 0, stream>>>(x, Xb0, n8);

    // ---- binned CSR build (r7-proven) ----
    const int nc1 = (E + CHUNK - 1) / CHUNK;
    const int nc2 = (E2 + CHUNK - 1) / CHUNK;
    const int nbk_used = (2 * N + (1 << BSHIFT) - 1) >> BSHIFT;   // <= NBK

    hipMemsetAsync(bcnt, 0, NBK * sizeof(int), stream);
    p0_bhist_k<<<256, 256, 0, stream>>>(ei + E, ei2 + E2, bcnt, N, E, E2);
    bscan_k<<<1, NBK, 0, stream>>>(bcnt, bktbase, cursor, rowptr, 2 * N, ET);
    p1_bin_k<<<nc1 + nc2, 256, 0, stream>>>(ei, ei + E, ea, ei2, ei2 + E2, ea2,
                                            cursor, binned, N, E, E2, nc1);
    p2_final_k<<<nbk_used, 256, 0, stream>>>(binned, bktbase, rowptr, pairs, 2 * N);

    // ---- 3 inception blocks: standalone gather + lean GEMM per layer ----
    const int gGather = (N + 15) / 16;
    const int gGemm   = (N + 63) / 64;

    const short* cur = Xb0;
    for (int b = 0; b < 3; ++b) {
        const float* lnb = (const float*)d_in[5 + 6 * b + 1];
        const float* c1b = (const float*)d_in[5 + 6 * b + 3];
        const float* c2b = (const float*)d_in[5 + 6 * b + 5];

        gatherX_k<<<gGather, 256, 0, stream>>>(cur, pairs, rowptr, G1, G2, N);

        float* yf = (b == 2) ? OUT : nullptr;
        short* yb = (b == 2) ? nullptr : ((cur == Xb0) ? Xb1 : Xb0);

        gemm_k<<<gGemm, 256, 0, stream>>>(
            cur, G1, G2, WT + (size_t)b * 49152, lnb, c1b, c2b, yf, yb, N);

        if (b < 2) cur = yb;
    }
}

// Round 12
// 754.319 us; speedup vs baseline: 1.2486x; 1.0562x over previous
//
#include <hip/hip_runtime.h>

#define DIM 128
#define CHUNK 8192          // edges per P1 block
#define NBK 256             // padded bucket count (used: ceil(2N/1024) = 196)
#define BSHIFT 10           // bucket covers 1024 virtual dst ids

typedef __attribute__((ext_vector_type(8))) short bf16x8;
typedef __attribute__((ext_vector_type(4))) float f32x4;
typedef __attribute__((ext_vector_type(2))) unsigned u32x2;
typedef __attribute__((ext_vector_type(4))) unsigned u32x4;

static __device__ __forceinline__ short f2bf(float f) {
    union { float f; unsigned u; } v; v.f = f;
    unsigned r = (v.u + 0x7FFF + ((v.u >> 16) & 1)) >> 16;   // RN-even
    return (short)r;
}
static __device__ __forceinline__ float asf(unsigned u) {
    union { unsigned u; float f; } v; v.u = u; return v.f;
}
static __device__ __forceinline__ unsigned asu(float f) {
    union { float f; unsigned u; } v; v.f = f; return v.u;
}
static __device__ __forceinline__ unsigned pk2(float a, float b) {
    return (unsigned)(unsigned short)f2bf(a) | ((unsigned)(unsigned short)f2bf(b) << 16);
}

// ------------- weight prep: pack 3 mats/layer as K=384 x N=128 bf16 --------
struct WPtrs { const float* w[9]; };
__global__ __launch_bounds__(256) void prep_w_k(WPtrs p, short* __restrict__ wt)
{
    const int g = blockIdx.x * 256 + threadIdx.x;   // 3*12*8*64 = 18432
    if (g >= 3 * 12 * 8 * 64) return;
    const int lane = g & 63;
    const int ct   = (g >> 6) & 7;
    const int rest = g >> 9;           // 0..35
    const int ks   = rest % 12;
    const int layer = rest / 12;
    const int mat   = ks >> 2;         // 0..2 within layer (128 rows = 4 ks each)
    const int n     = ct * 16 + (lane & 15);
    const int kbase = (ks & 3) * 32 + (lane >> 4) * 8;
    const float* W = p.w[layer * 3 + mat];
    short* dst = wt + (size_t)layer * 49152 + ks * 4096 + ct * 512 + lane * 8;
#pragma unroll
    for (int j = 0; j < 8; ++j) dst[j] = f2bf(W[(size_t)(kbase + j) * DIM + n]);
}

// ------------- fp32 -> bf16 cast of the input features ----------------------
__global__ __launch_bounds__(256) void cast_k(
    const float* __restrict__ X, short* __restrict__ Xb, int n8)
{
    const int i = blockIdx.x * 256 + threadIdx.x;
    if (i >= n8) return;
    const float4* xp = (const float4*)X + (size_t)i * 2;
    const float4 a = xp[0];
    const float4 b = xp[1];
    bf16x8 v;
    v[0] = f2bf(a.x); v[1] = f2bf(a.y); v[2] = f2bf(a.z); v[3] = f2bf(a.w);
    v[4] = f2bf(b.x); v[5] = f2bf(b.y); v[6] = f2bf(b.z); v[7] = f2bf(b.w);
    *(bf16x8*)(Xb + (size_t)i * 8) = v;
}

// =================== binned CSR build (r7 structure, wider blocks) ==========
// virtual dst id v in [0, 2N): v = dst (adj1), N + dst (adj2).
// bucket = v >> 10 (196 used); vlow = v & 1023.
// binned elem: x = src | (vlow << 17)   (src < 2^17), y = w bits.

__global__ __launch_bounds__(256) void p0_bhist_k(
    const int* __restrict__ d1, const int* __restrict__ d2,
    int* __restrict__ bcnt, int N, int E, int E2)
{
    __shared__ int lh[NBK];
    const int t = threadIdx.x;
    lh[t] = 0;
    __syncthreads();
    const int stride = gridDim.x * 256;
    for (int i = blockIdx.x * 256 + t; i < E;  i += stride) atomicAdd(&lh[d1[i] >> BSHIFT], 1);
    for (int i = blockIdx.x * 256 + t; i < E2; i += stride) atomicAdd(&lh[(N + d2[i]) >> BSHIFT], 1);
    __syncthreads();
    if (lh[t]) atomicAdd(&bcnt[t], lh[t]);
}

__global__ __launch_bounds__(256) void bscan_k(
    const int* __restrict__ bcnt, int* __restrict__ bktbase,
    int* __restrict__ cursor, int* __restrict__ rowptr, int twoN, int ET)
{
    __shared__ int sv[NBK];
    const int t = threadIdx.x;
    sv[t] = bcnt[t];
    __syncthreads();
    for (int off = 1; off < NBK; off <<= 1) {
        int a = (t >= off) ? sv[t - off] : 0;
        __syncthreads();
        sv[t] += a;
        __syncthreads();
    }
    const int excl = t ? sv[t - 1] : 0;
    bktbase[t] = excl;
    cursor[t]  = excl;
    if (t == 0) rowptr[twoN] = ET;
}

// 512 threads/block: 16 edges/thread; 76 KB LDS -> 2 blocks/CU = 1024 thr/CU.
__global__ __launch_bounds__(512) void p1_bin_k(
    const int* __restrict__ s1, const int* __restrict__ d1, const float* __restrict__ ea1,
    const int* __restrict__ s2, const int* __restrict__ d2, const float* __restrict__ ea2,
    int* __restrict__ cursor, uint2* __restrict__ binned,
    int N, int E, int E2, int nc1)
{
    __shared__ __align__(16) uint2 stage[CHUNK];     // 64 KB
    __shared__ unsigned char lbkt[CHUNK];            // 8 KB
    __shared__ int hist[NBK], exclv[NBK], lcur[NBK], gpos[NBK];

    const int t = threadIdx.x;
    const int c = blockIdx.x;
    const bool a2 = (c >= nc1);
    const int* S  = a2 ? s2  : s1;
    const int* D  = a2 ? d2  : d1;
    const float* W = a2 ? ea2 : ea1;
    const int Eloc = a2 ? E2 : E;
    const int voff = a2 ? N : 0;
    const int eb   = (a2 ? (c - nc1) : c) * CHUNK;
    const int ec   = min(CHUNK, Eloc - eb);

    if (t < NBK) hist[t] = 0;
    __syncthreads();

    for (int i = t; i < ec; i += 512)
        atomicAdd(&hist[(unsigned)(voff + D[eb + i]) >> BSHIFT], 1);
    __syncthreads();

    if (t < NBK) exclv[t] = hist[t];
    __syncthreads();
    for (int off = 1; off < NBK; off <<= 1) {
        const int a = (t < NBK && t >= off) ? exclv[t - off] : 0;
        __syncthreads();
        if (t < NBK) exclv[t] += a;
        __syncthreads();
    }
    if (t < NBK) {
        const int myincl = exclv[t];
        const int excl = myincl - hist[t];
        exclv[t] = excl;
        lcur[t]  = excl;
        if (hist[t]) gpos[t] = atomicAdd(&cursor[t], hist[t]);
    }
    __syncthreads();

    for (int i = t; i < ec; i += 512) {
        const int v = voff + D[eb + i];
        const int b = (unsigned)v >> BSHIFT;
        const int lpos = atomicAdd(&lcur[b], 1);
        stage[lpos] = make_uint2((unsigned)S[eb + i] | ((unsigned)(v & 1023) << 17),
                                 asu(W[eb + i]));
        lbkt[lpos] = (unsigned char)b;
    }
    __syncthreads();

    for (int s = t; s < ec; s += 512) {
        const int b = lbkt[s];
        binned[gpos[b] + (s - exclv[b])] = stage[s];
    }
}

// 1024 threads/block: 1 bin/thread; scan = 10 iters x 2 barriers at 4x width.
__global__ __launch_bounds__(1024) void p2_final_k(
    const uint2* __restrict__ binned, const int* __restrict__ bktbase,
    int* __restrict__ rowptr, uint2* __restrict__ pairs, int twoN)
{
    __shared__ int hist[1024], scn[1024], lcur[1024];
    const int t = threadIdx.x;
    const int b = blockIdx.x;
    const int base = bktbase[b];
    const int cnt  = bktbase[b + 1] - base;
    const int vbase = b << BSHIFT;

    hist[t] = 0;
    __syncthreads();

    for (int i = t; i < cnt; i += 1024)
        atomicAdd(&hist[binned[base + i].x >> 17], 1);
    __syncthreads();

    scn[t] = hist[t];
    __syncthreads();
    for (int off = 1; off < 1024; off <<= 1) {
        const int a = (t >= off) ? scn[t - off] : 0;
        __syncthreads();
        scn[t] += a;
        __syncthreads();
    }
    {
        const int excl = scn[t] - hist[t];
        lcur[t] = excl;
        const int v = vbase + t;
        if (v < twoN) rowptr[v] = base + excl;
    }
    __syncthreads();

    for (int i = t; i < cnt; i += 1024) {
        const uint2 e = binned[base + i];
        const int vlow = e.x >> 17;
        const int pos = base + atomicAdd(&lcur[vlow], 1);
        pairs[pos] = make_uint2(e.x & 0x1FFFFu, e.y);
    }
}

// ---------------- gather inner loop (16 lanes per node, 16 B/lane) ----------
static __device__ __forceinline__ void bf2acc8(unsigned w, u32x4 h, float* acc)
{
    const float wf = asf(w);
    acc[0] = fmaf(wf, asf(h.x << 16),         acc[0]);
    acc[1] = fmaf(wf, asf(h.x & 0xFFFF0000u), acc[1]);
    acc[2] = fmaf(wf, asf(h.y << 16),         acc[2]);
    acc[3] = fmaf(wf, asf(h.y & 0xFFFF0000u), acc[3]);
    acc[4] = fmaf(wf, asf(h.z << 16),         acc[4]);
    acc[5] = fmaf(wf, asf(h.z & 0xFFFF0000u), acc[5]);
    acc[6] = fmaf(wf, asf(h.w << 16),         acc[6]);
    acc[7] = fmaf(wf, asf(h.w & 0xFFFF0000u), acc[7]);
}

static __device__ __forceinline__ void gacc16(
    const short* __restrict__ H, const uint2* __restrict__ pairs,
    int start, int end, int s, float* acc)
{
    int j = start;
    for (; j + 7 < end; j += 8) {
        u32x2 p[8]; u32x4 h[8];
#pragma unroll
        for (int q = 0; q < 8; ++q)
            p[q] = __builtin_nontemporal_load((const u32x2*)(pairs + j + q));
#pragma unroll
        for (int q = 0; q < 8; ++q)
            h[q] = *(const u32x4*)(H + (size_t)p[q].x * DIM + s * 8);
#pragma unroll
        for (int q = 0; q < 8; ++q) bf2acc8(p[q].y, h[q], acc);
    }
    if (j + 3 < end) {
        u32x2 p[4]; u32x4 h[4];
#pragma unroll
        for (int q = 0; q < 4; ++q)
            p[q] = __builtin_nontemporal_load((const u32x2*)(pairs + j + q));
#pragma unroll
        for (int q = 0; q < 4; ++q)
            h[q] = *(const u32x4*)(H + (size_t)p[q].x * DIM + s * 8);
#pragma unroll
        for (int q = 0; q < 4; ++q) bf2acc8(p[q].y, h[q], acc);
        j += 4;
    }
    for (; j < end; ++j) {
        const u32x2 p = __builtin_nontemporal_load((const u32x2*)(pairs + j));
        const u32x4 h = *(const u32x4*)(H + (size_t)p.x * DIM + s * 8);
        bf2acc8(p.y, h, acc);
    }
}

// ------------- fused layer (r7-proven): gather G1,G2 -> LDS, K=384 MFMA -----
// Y = [Xb | G1 | G2] @ [W0;W1;W2] + (b0+b1+b2).
// 33% occupancy is the L2-friendly operating point (r8/r9: higher occ
// inflates FETCH+WRITE and is slower). Do not raise concurrency here.
__global__ __launch_bounds__(256, 5) void fused_layer_k(
    const short* __restrict__ Xb, const short* __restrict__ Wp,
    const uint2* __restrict__ pairs, const int* __restrict__ rowptr,
    const float* __restrict__ b0, const float* __restrict__ b1,
    const float* __restrict__ b2,
    float* __restrict__ Yf, short* __restrict__ Yb, int N)
{
    __shared__ __align__(16) short As[64][256];   // G1 slots 0..15, G2 slots 16..31 (16B slots)
    const int t  = threadIdx.x;
    const int m0 = blockIdx.x * 64;

    // ---- gather phase: 16 lanes/node, 16 nodes concurrent, 4 groups ----
    const int s    = t & 15;
    const int nrow = t >> 4;              // 0..15
#pragma unroll
    for (int nl = 0; nl < 4; ++nl) {
        const int r    = nl * 16 + nrow;
        const int node = m0 + r;
        float a1[8] = {0.f,0.f,0.f,0.f,0.f,0.f,0.f,0.f};
        float a2[8] = {0.f,0.f,0.f,0.f,0.f,0.f,0.f,0.f};
        if (node < N) {
            gacc16(Xb, pairs, rowptr[node],     rowptr[node + 1],     s, a1);
            gacc16(Xb, pairs, rowptr[N + node], rowptr[N + node + 1], s, a2);
        }
        u32x4 o1 = (u32x4){pk2(a1[0], a1[1]), pk2(a1[2], a1[3]),
                           pk2(a1[4], a1[5]), pk2(a1[6], a1[7])};
        u32x4 o2 = (u32x4){pk2(a2[0], a2[1]), pk2(a2[2], a2[3]),
                           pk2(a2[4], a2[5]), pk2(a2[6], a2[7])};
        const int sw = s ^ (r & 7);
        *(u32x4*)&As[r][sw * 8]        = o1;
        *(u32x4*)&As[r][128 + sw * 8]  = o2;   // slot 16+sw
    }
    __syncthreads();

    // ---- MFMA phase ----
    const int wave  = t >> 6;
    const int lane  = t & 63;
    const int l15   = lane & 15;
    const int kq    = lane >> 4;
    const int mbase = wave * 16;
    const int mrow  = m0 + mbase + l15;
    const int mclmp = (mrow < N) ? mrow : (N - 1);
    const short* xrow = Xb + (size_t)mclmp * DIM + kq * 8;

    f32x4 acc[8];
#pragma unroll
    for (int ct = 0; ct < 8; ++ct) acc[ct] = (f32x4){0.f, 0.f, 0.f, 0.f};

#pragma unroll
    for (int ks = 0; ks < 4; ++ks) {
        const bf16x8 a = *(const bf16x8*)(xrow + ks * 32);
        const short* wb = Wp + ks * 4096 + lane * 8;
#pragma unroll
        for (int ct = 0; ct < 8; ++ct)
            acc[ct] = __builtin_amdgcn_mfma_f32_16x16x32_bf16(
                a, *(const bf16x8*)(wb + ct * 512), acc[ct], 0, 0, 0);
    }
#pragma unroll
    for (int ks = 4; ks < 12; ++ks) {
        const int lin  = (ks - 4) * 4 + kq;          // 0..31
        const int row  = mbase + l15;
        const int slot = (lin & 16) | ((lin & 15) ^ (row & 7));
        const bf16x8 a = *(const bf16x8*)&As[row][slot * 8];
        const short* wb = Wp + ks * 4096 + lane * 8;
#pragma unroll
        for (int ct = 0; ct < 8; ++ct)
            acc[ct] = __builtin_amdgcn_mfma_f32_16x16x32_bf16(
                a, *(const bf16x8*)(wb + ct * 512), acc[ct], 0, 0, 0);
    }

    // D: col = ct*16 + (lane&15), row = (lane>>4)*4 + r
#pragma unroll
    for (int ct = 0; ct < 8; ++ct) {
        const int col = ct * 16 + l15;
        const float bias = b0[col] + b1[col] + b2[col];
#pragma unroll
        for (int r = 0; r < 4; ++r) {
            const int m = m0 + mbase + kq * 4 + r;
            if (m >= N) continue;
            const float v = acc[ct][r] + bias;
            if (Yf) __builtin_nontemporal_store(v, &Yf[(size_t)m * DIM + col]);
            else    Yb[(size_t)m * DIM + col] = f2bf(v);
        }
    }
}

extern "C" void kernel_launch(void* const* d_in, const int* in_sizes, int n_in,
                              void* d_out, int out_size, void* d_ws, size_t ws_size,
                              hipStream_t stream)
{
    const float* x   = (const float*)d_in[0];
    const int*   ei  = (const int*)d_in[1];
    const float* ea  = (const float*)d_in[2];
    const int*   ei2 = (const int*)d_in[3];
    const float* ea2 = (const float*)d_in[4];

    const int N  = in_sizes[0] / DIM;
    const int E  = in_sizes[2];
    const int E2 = in_sizes[4];
    const int ET = E + E2;

    float* OUT = (float*)d_out;

    // ---- workspace layout (~103.5 MB) ----
    short* Xb0 = (short*)d_ws;                        // N*DIM bf16
    short* Xb1 = Xb0 + (size_t)N * DIM;               // N*DIM bf16
    short* WT  = Xb1 + (size_t)N * DIM;               // 3*49152 bf16 (packed K=384)
    int*   rowptr = (int*)(WT + 3 * 49152);           // 2N+1 (padded to 2N+4)
    int*   bcnt   = rowptr + 2 * N + 4;               // NBK
    int*   bktbase= bcnt + NBK;                       // NBK+1 -> pad to NBK+4
    int*   cursor = bktbase + NBK + 4;                // NBK
    uint2* pairs  = (uint2*)(cursor + NBK);           // ET * 8B
    uint2* binned = pairs + ET;                       // ET * 8B (dead after CSR build)

    // ---- weight prep ----
    WPtrs wp;
    for (int b = 0; b < 3; ++b) {
        wp.w[b * 3 + 0] = (const float*)d_in[5 + 6 * b + 0];
        wp.w[b * 3 + 1] = (const float*)d_in[5 + 6 * b + 2];
        wp.w[b * 3 + 2] = (const float*)d_in[5 + 6 * b + 4];
    }
    prep_w_k<<<(18432 + 255) / 256, 256, 0, stream>>>(wp, WT);

    // ---- input cast to bf16 ----
    const int n8 = N * DIM / 8;
    cast_k<<<(n8 + 255) / 256, 256, 0, stream>>>(x, Xb0, n8);

    // ---- binned CSR build ----
    const int nc1 = (E + CHUNK - 1) / CHUNK;
    const int nc2 = (E2 + CHUNK - 1) / CHUNK;
    const int nbk_used = (2 * N + (1 << BSHIFT) - 1) >> BSHIFT;   // <= NBK

    hipMemsetAsync(bcnt, 0, NBK * sizeof(int), stream);
    p0_bhist_k<<<256, 256, 0, stream>>>(ei + E, ei2 + E2, bcnt, N, E, E2);
    bscan_k<<<1, NBK, 0, stream>>>(bcnt, bktbase, cursor, rowptr, 2 * N, ET);
    p1_bin_k<<<nc1 + nc2, 512, 0, stream>>>(ei, ei + E, ea, ei2, ei2 + E2, ea2,
                                            cursor, binned, N, E, E2, nc1);
    p2_final_k<<<nbk_used, 1024, 0, stream>>>(binned, bktbase, rowptr, pairs, 2 * N);

    // ---- 3 inception blocks: fused gather + K=384 GEMM per layer ----
    const int gGemm = (N + 63) / 64;

    const short* cur = Xb0;
    for (int b = 0; b < 3; ++b) {
        const float* lnb = (const float*)d_in[5 + 6 * b + 1];
        const float* c1b = (const float*)d_in[5 + 6 * b + 3];
        const float* c2b = (const float*)d_in[5 + 6 * b + 5];

        float* yf = (b == 2) ? OUT : nullptr;
        short* yb = (b == 2) ? nullptr : ((cur == Xb0) ? Xb1 : Xb0);

        fused_layer_k<<<gGemm, 256, 0, stream>>>(
            cur, WT + (size_t)b * 49152, pairs, rowptr, lnb, c1b, c2b, yf, yb, N);

        if (b < 2) cur = yb;
    }
}